// Round 7
// baseline (182.928 us; speedup 1.0000x reference)
//
#include <hip/hip_runtime.h>
#include <hip/hip_bf16.h>
#include <cstddef>
#include <cstdint>

constexpr int Tt = 8192;
constexpr int Dd = 768;
constexpr int Nn = 10000;
constexpr int Ww = 32;

typedef __bf16 bf16x8 __attribute__((ext_vector_type(8)));
typedef __bf16 bf16x4 __attribute__((ext_vector_type(4)));
typedef _Float16 half8v __attribute__((ext_vector_type(8)));
typedef _Float16 half4v __attribute__((ext_vector_type(4)));
typedef float f32x4 __attribute__((ext_vector_type(4)));

#define MFMA16(a, b, c) __builtin_amdgcn_mfma_f32_16x16x32_bf16((a), (b), (c), 0, 0, 0)
#define MFMAH(a, b, c) __builtin_amdgcn_mfma_f32_16x16x32_f16((a), (b), (c), 0, 0, 0)

// Async global->LDS, 16B per lane. LDS dest is wave-uniform base + lane*16
// (m104/m108) — all uses below keep dest lane-linear by construction.
// MUST be followed by s_waitcnt vmcnt(0) before any dependent barrier:
// the compiler does not model the LDS side-effect (round-3 replay race).
template <typename T>
__device__ inline void gll16(const T* g, T* l) {
    __builtin_amdgcn_global_load_lds(
        (const __attribute__((address_space(1))) void*)g,
        (__attribute__((address_space(3))) void*)l, 16, 0, 0);
}
__device__ inline void vmdrain() {
    asm volatile("s_waitcnt vmcnt(0)" ::: "memory");
}

// ---------------------------------------------------------------------------
// Fused converter: emb -> (Eh, El bf16 pair + Ef fp16); Wq -> (Wh, Wl pair).
// ---------------------------------------------------------------------------
__global__ __launch_bounds__(256) void conv_fused_kernel(const float* __restrict__ emb,
                                                         const float* __restrict__ Wq,
                                                         __bf16* __restrict__ Eh,
                                                         __bf16* __restrict__ El,
                                                         _Float16* __restrict__ Ef,
                                                         __bf16* __restrict__ Wh,
                                                         __bf16* __restrict__ Wl) {
    const int nE = (Tt * Dd) / 4;
    const int nW = (Dd * Dd) / 4;
    const int i = blockIdx.x * 256 + threadIdx.x;
    if (i < nE) {
        const float4 v = reinterpret_cast<const float4*>(emb)[i];
        const float vv[4] = {v.x, v.y, v.z, v.w};
        bf16x4 oh, ol;
        half4v of;
#pragma unroll
        for (int j = 0; j < 4; ++j) {
            oh[j] = (__bf16)vv[j];
            ol[j] = (__bf16)(vv[j] - (float)oh[j]);
            of[j] = (_Float16)vv[j];
        }
        reinterpret_cast<bf16x4*>(Eh)[i] = oh;
        reinterpret_cast<bf16x4*>(El)[i] = ol;
        reinterpret_cast<half4v*>(Ef)[i] = of;
    } else {
        const int j4 = i - nE;
        if (j4 < nW) {
            const float4 v = reinterpret_cast<const float4*>(Wq)[j4];
            const float vv[4] = {v.x, v.y, v.z, v.w};
            bf16x4 oh, ol;
#pragma unroll
            for (int j = 0; j < 4; ++j) {
                oh[j] = (__bf16)vv[j];
                ol[j] = (__bf16)(vv[j] - (float)oh[j]);
            }
            reinterpret_cast<bf16x4*>(Wh)[j4] = oh;
            reinterpret_cast<bf16x4*>(Wl)[j4] = ol;
        }
    }
}

// Simple converter for fallback tiers.
template <bool LO>
__global__ __launch_bounds__(256) void conv_kernel(const float* __restrict__ src,
                                                   __bf16* __restrict__ h,
                                                   __bf16* __restrict__ l, int n4) {
    const int i = blockIdx.x * 256 + threadIdx.x;
    if (i >= n4) return;
    const float4 v = reinterpret_cast<const float4*>(src)[i];
    bf16x4 oh, ol;
    oh[0] = (__bf16)v.x; oh[1] = (__bf16)v.y; oh[2] = (__bf16)v.z; oh[3] = (__bf16)v.w;
    reinterpret_cast<bf16x4*>(h)[i] = oh;
    if (LO) {
        ol[0] = (__bf16)(v.x - (float)oh[0]);
        ol[1] = (__bf16)(v.y - (float)oh[1]);
        ol[2] = (__bf16)(v.z - (float)oh[2]);
        ol[3] = (__bf16)(v.w - (float)oh[3]);
        reinterpret_cast<bf16x4*>(l)[i] = ol;
    }
}

// ---------------------------------------------------------------------------
// Counting sort of span indices by start. Rebuilt fully every call.
// ---------------------------------------------------------------------------
__global__ __launch_bounds__(256) void zero_kernel(int* __restrict__ p, int n) {
    const int i = blockIdx.x * 256 + threadIdx.x;
    if (i < n) p[i] = 0;
}

__global__ __launch_bounds__(256) void hist_kernel(const int* __restrict__ spans,
                                                   int* __restrict__ hist) {
    const int i = blockIdx.x * 256 + threadIdx.x;
    if (i < Nn) atomicAdd(&hist[spans[2 * i]], 1);
}

__global__ __launch_bounds__(256) void scan_kernel(int* __restrict__ hist) {
    __shared__ int part[256];
    const int t = threadIdx.x;
    int vals[32];
    int sum = 0;
#pragma unroll
    for (int i = 0; i < 32; ++i) { vals[i] = hist[t * 32 + i]; sum += vals[i]; }
    part[t] = sum;
    __syncthreads();
    for (int off = 1; off < 256; off <<= 1) {
        const int v = (t >= off) ? part[t - off] : 0;
        __syncthreads();
        part[t] += v;
        __syncthreads();
    }
    int run = (t == 0) ? 0 : part[t - 1];
#pragma unroll
    for (int i = 0; i < 32; ++i) { const int v = vals[i]; hist[t * 32 + i] = run; run += v; }
}

__global__ __launch_bounds__(256) void scatter_kernel(const int* __restrict__ spans,
                                                      int* __restrict__ offs,
                                                      int* __restrict__ perm) {
    const int i = blockIdx.x * 256 + threadIdx.x;
    if (i < Nn) {
        const int p = atomicAdd(&offs[spans[2 * i]], 1);
        perm[p] = i;
    }
}

// ---------------------------------------------------------------------------
// fp32 vector qproj (fallback tiers). Q = emb @ Wq^T + bq, bf16 hi/lo out.
// ---------------------------------------------------------------------------
template <bool SPLIT>
__global__ __launch_bounds__(256) void qproj_kernel(const float* __restrict__ emb,
                                                    const float* __restrict__ Wq,
                                                    const float* __restrict__ bq,
                                                    __bf16* __restrict__ Qh,
                                                    __bf16* __restrict__ Ql) {
    __shared__ float As[64][32];
    __shared__ float Bs[64][32];
    const int tid = threadIdx.x;
    const int tx = tid & 15;
    const int ty = tid >> 4;
    const int m0 = blockIdx.x * 64;
    const int n0 = blockIdx.y * 64;

    float acc[4][4] = {};

    for (int kc = 0; kc < Dd; kc += 32) {
#pragma unroll
        for (int i = 0; i < 2; ++i) {
            const int f   = tid + i * 256;
            const int row = f >> 3;
            const int c4  = f & 7;
            const int ph  = (c4 + (row >> 2)) & 7;
            *reinterpret_cast<float4*>(&As[row][ph * 4]) =
                *reinterpret_cast<const float4*>(&emb[(size_t)(m0 + row) * Dd + kc + c4 * 4]);
            *reinterpret_cast<float4*>(&Bs[row][ph * 4]) =
                *reinterpret_cast<const float4*>(&Wq[(size_t)(n0 + row) * Dd + kc + c4 * 4]);
        }
        __syncthreads();
#pragma unroll
        for (int d4 = 0; d4 < 8; ++d4) {
            float4 av[4], bv[4];
#pragma unroll
            for (int r = 0; r < 4; ++r)
                av[r] = *reinterpret_cast<const float4*>(&As[ty * 4 + r][((d4 + ty) & 7) * 4]);
#pragma unroll
            for (int c = 0; c < 4; ++c)
                bv[c] = *reinterpret_cast<const float4*>(&Bs[tx * 4 + c][((d4 + tx) & 7) * 4]);
#pragma unroll
            for (int r = 0; r < 4; ++r)
#pragma unroll
                for (int c = 0; c < 4; ++c) {
                    acc[r][c] += av[r].x * bv[c].x;
                    acc[r][c] += av[r].y * bv[c].y;
                    acc[r][c] += av[r].z * bv[c].z;
                    acc[r][c] += av[r].w * bv[c].w;
                }
        }
        __syncthreads();
    }
#pragma unroll
    for (int r = 0; r < 4; ++r) {
        bf16x4 oh, ol;
#pragma unroll
        for (int c = 0; c < 4; ++c) {
            const float v = acc[r][c] + bq[n0 + tx * 4 + c];
            const __bf16 h = (__bf16)v;
            oh[c] = h;
            if (SPLIT) ol[c] = (__bf16)(v - (float)h);
        }
        const size_t off = (size_t)(m0 + ty * 4 + r) * Dd + n0 + tx * 4;
        *reinterpret_cast<bf16x4*>(&Qh[off]) = oh;
        if (SPLIT) *reinterpret_cast<bf16x4*>(&Ql[off]) = ol;
    }
}

// ---------------------------------------------------------------------------
// MFMA qproj v5: 128x128 block, 4 waves x 64x64, BK=32, double-buffered
// global_load_lds staging with explicit vmcnt(0) drain before the barrier,
// source-permuted columns (gc = c ^ ((r>>1)&3)) for 2-way fragment reads.
// 3-term bf16 split, fp16 output. Grid 384 (all blocks co-resident).
// ---------------------------------------------------------------------------
__global__ __launch_bounds__(256) void qproj_mfma3_kernel(const __bf16* __restrict__ Eh,
                                                          const __bf16* __restrict__ El,
                                                          const __bf16* __restrict__ Wh,
                                                          const __bf16* __restrict__ Wl,
                                                          const float* __restrict__ bq,
                                                          _Float16* __restrict__ Qf) {
    __shared__ __align__(16) __bf16 Ahs[2][128 * 32];
    __shared__ __align__(16) __bf16 Als[2][128 * 32];
    __shared__ __align__(16) __bf16 Bhs[2][128 * 32];
    __shared__ __align__(16) __bf16 Bls[2][128 * 32];

    const int tid  = threadIdx.x;
    const int wave = tid >> 6;
    const int lane = tid & 63;

    const int b   = blockIdx.x;       // 0..383
    const int xcd = b & 7;
    const int li  = b >> 3;           // 0..47
    const int mt  = xcd * 8 + li / 6; // 0..63
    const int nt  = li % 6;           // 0..5
    const int m0 = mt * 128;
    const int n0 = nt * 128;
    const int wm = (wave & 1) * 64;
    const int wn = (wave >> 1) * 64;
    const int fr = lane & 15;
    const int kg = lane >> 4;

    // Staging geometry: 512 segs (16B) per array; 2 segs/thread (s = tid + i*256).
    int srow[2], sgc[2];
#pragma unroll
    for (int i = 0; i < 2; ++i) {
        const int s = tid + i * 256;
        srow[i] = s >> 2;
        sgc[i]  = ((s & 3) ^ ((srow[i] >> 1) & 3)) * 8;
    }

    auto issue = [&](int kc, int buf) {
#pragma unroll
        for (int i = 0; i < 2; ++i) {
            const int s = tid + i * 256;
            const size_t ga = (size_t)(m0 + srow[i]) * Dd + kc + sgc[i];
            const size_t gb = (size_t)(n0 + srow[i]) * Dd + kc + sgc[i];
            gll16(Eh + ga, &Ahs[buf][s * 8]);
            gll16(El + ga, &Als[buf][s * 8]);
            gll16(Wh + gb, &Bhs[buf][s * 8]);
            gll16(Wl + gb, &Bls[buf][s * 8]);
        }
    };

    issue(0, 0);

    f32x4 acc[4][4] = {};

    for (int kc = 0; kc < Dd; kc += 32) {
        const int buf = (kc >> 5) & 1;
        vmdrain();        // all DMAs for `buf` landed (this wave)
        __syncthreads();  // ... for all waves
        if (kc + 32 < Dd) issue(kc + 32, buf ^ 1);  // overlaps MFMA below

        bf16x8 ah[4], al[4], bh[4], bl[4];
#pragma unroll
        for (int r = 0; r < 4; ++r) {
            const int R = wm + r * 16 + fr;
            const int p = (kg ^ ((R >> 1) & 3)) * 8;
            ah[r] = *reinterpret_cast<const bf16x8*>(&Ahs[buf][R * 32 + p]);
            al[r] = *reinterpret_cast<const bf16x8*>(&Als[buf][R * 32 + p]);
        }
#pragma unroll
        for (int c = 0; c < 4; ++c) {
            const int R = wn + c * 16 + fr;
            const int p = (kg ^ ((R >> 1) & 3)) * 8;
            bh[c] = *reinterpret_cast<const bf16x8*>(&Bhs[buf][R * 32 + p]);
            bl[c] = *reinterpret_cast<const bf16x8*>(&Bls[buf][R * 32 + p]);
        }
#pragma unroll
        for (int r = 0; r < 4; ++r)
#pragma unroll
            for (int c = 0; c < 4; ++c) {
                acc[r][c] = MFMA16(ah[r], bh[c], acc[r][c]);
                acc[r][c] = MFMA16(al[r], bh[c], acc[r][c]);
                acc[r][c] = MFMA16(ah[r], bl[c], acc[r][c]);
            }
    }

    // Epilogue: C/D layout col=lane&15, row=(lane>>4)*4+reg.
#pragma unroll
    for (int c = 0; c < 4; ++c) {
        const int ocol = n0 + wn + c * 16 + fr;
        const float bqv = bq[ocol];
#pragma unroll
        for (int r = 0; r < 4; ++r)
#pragma unroll
            for (int j = 0; j < 4; ++j) {
                const int orow = m0 + wm + r * 16 + kg * 4 + j;
                Qf[(size_t)orow * Dd + ocol] = (_Float16)(acc[r][c][j] + bqv);
            }
    }
}

// ---------------------------------------------------------------------------
// Span attention v4: window-shared LDS via double-buffered global_load_lds,
// source-permuted columns (gc = c ^ (r&7), ST=128) -> 2-way fragment reads.
// One barrier per chunk; explicit vmcnt(0) drain. Softmax/col-sums in regs.
// ---------------------------------------------------------------------------
__global__ __launch_bounds__(256) void span_attn_win2_kernel(const _Float16* __restrict__ Ef,
                                                             const int* __restrict__ spans,
                                                             const _Float16* __restrict__ Qf,
                                                             const int* __restrict__ perm,
                                                             float* __restrict__ out) {
    constexpr int WR = 48, CH = 128, NCH = Dd / CH;
    __shared__ __align__(16) _Float16 Qs[2][WR * CH];
    __shared__ __align__(16) _Float16 Es[2][WR * CH];

    const int tid  = threadIdx.x;
    const int wave = tid >> 6;
    const int lane = tid & 63;

    const int b     = blockIdx.x;
    const int bp    = (b & 7) * 313 + (b >> 3);
    const int slot0 = bp * 4;
    const int slot  = slot0 + wave;
    const bool active = slot < Nn;

    int s0 = perm[slot0 < Nn ? slot0 : (Nn - 1)];
    if ((unsigned)s0 >= (unsigned)Nn) s0 = 0;
    int s = active ? perm[slot] : s0;
    if ((unsigned)s >= (unsigned)Nn) s = 0;

    const int w0    = spans[2 * s0];
    const int start = spans[2 * s];
    const int L     = spans[2 * s + 1] - start + 1;  // 1..32
    const bool big  = L > 16;
    const int sl    = start - w0;
    const bool inwin = active && sl >= 0 && sl <= (WR - 32);

    const int row = lane & 15;  // A-frag m; C-col k
    const int kq  = lane >> 4;

    const size_t gq = (size_t)(start + row) * Dd + kq * 8;  // fallback base

    // Staging: 768 segs per array per chunk; 3 segs/thread (s = tid + i*256).
    int srow[3], sgc[3];
#pragma unroll
    for (int i = 0; i < 3; ++i) {
        const int sg = tid + i * 256;
        srow[i] = sg >> 4;
        sgc[i]  = ((sg & 15) ^ (srow[i] & 7)) * 8;
    }
    auto issue = [&](int c, int buf) {
        const int c0 = c * CH;
#pragma unroll
        for (int i = 0; i < 3; ++i) {
            const int sg = tid + i * 256;
            int gr = w0 + srow[i];
            if (gr > Tt - 1) gr = Tt - 1;  // pad rows (never consumed)
            const size_t ga = (size_t)gr * Dd + c0 + sgc[i];
            gll16(Qf + ga, &Qs[buf][sg * 8]);
            gll16(Ef + ga, &Es[buf][sg * 8]);
        }
    };

    issue(0, 0);

    f32x4 acc00 = {0.f, 0.f, 0.f, 0.f};
    f32x4 acc01 = {0.f, 0.f, 0.f, 0.f};
    f32x4 acc10 = {0.f, 0.f, 0.f, 0.f};
    f32x4 acc11 = {0.f, 0.f, 0.f, 0.f};

    for (int c = 0; c < NCH; ++c) {
        const int buf = c & 1;
        vmdrain();
        __syncthreads();
        if (c + 1 < NCH) issue(c + 1, buf ^ 1);

        if (inwin) {
#pragma unroll
            for (int j = 0; j < 4; ++j) {
                const int R0 = sl + row;
                const int p0 = ((kq + 4 * j) ^ (R0 & 7)) * 8;
                const half8v a0 = *reinterpret_cast<const half8v*>(&Qs[buf][R0 * CH + p0]);
                const half8v b0 = *reinterpret_cast<const half8v*>(&Es[buf][R0 * CH + p0]);
                acc00 = MFMAH(a0, b0, acc00);
                if (big) {
                    const int R1 = R0 + 16;
                    const int p1 = ((kq + 4 * j) ^ (R1 & 7)) * 8;
                    const half8v a1 = *reinterpret_cast<const half8v*>(&Qs[buf][R1 * CH + p1]);
                    const half8v b1 = *reinterpret_cast<const half8v*>(&Es[buf][R1 * CH + p1]);
                    acc01 = MFMAH(a0, b1, acc01);
                    acc10 = MFMAH(a1, b0, acc10);
                    acc11 = MFMAH(a1, b1, acc11);
                }
            }
        } else if (active) {
            const int c0 = c * CH;
#pragma unroll
            for (int j = 0; j < 4; ++j) {
                const int o = c0 + j * 32;
                const half8v a0 = *reinterpret_cast<const half8v*>(&Qf[gq + o]);
                const half8v b0 = *reinterpret_cast<const half8v*>(&Ef[gq + o]);
                acc00 = MFMAH(a0, b0, acc00);
                if (big) {
                    const half8v a1 = *reinterpret_cast<const half8v*>(&Qf[gq + 16 * Dd + o]);
                    const half8v b1 = *reinterpret_cast<const half8v*>(&Ef[gq + 16 * Dd + o]);
                    acc01 = MFMAH(a0, b1, acc01);
                    acc10 = MFMAH(a1, b0, acc10);
                    acc11 = MFMAH(a1, b1, acc11);
                }
            }
        }
    }

    // ---- In-register softmax + column sums (round-5/6 proven) ----
    const float NEG = -1e30f;
    const bool kv0 = row < L;
    const bool kv1 = (16 + row) < L;
    float cA, cB;
    {
        float w00[4], w01[4], w10[4], w11[4];
#pragma unroll
        for (int r = 0; r < 4; ++r) {
            float m = kv0 ? acc00[r] : NEG;
            if (big) m = fmaxf(m, kv1 ? acc01[r] : NEG);
#pragma unroll
            for (int st = 1; st <= 8; st <<= 1) m = fmaxf(m, __shfl_xor(m, st));
            const float e0 = kv0 ? __expf(acc00[r] - m) : 0.f;
            const float e1 = (big && kv1) ? __expf(acc01[r] - m) : 0.f;
            float sum = e0 + e1;
#pragma unroll
            for (int st = 1; st <= 8; st <<= 1) sum += __shfl_xor(sum, st);
            const float inv = 1.f / sum;
            const bool qv = (kq * 4 + r) < L;
            w00[r] = qv ? e0 * inv : 0.f;
            w01[r] = qv ? e1 * inv : 0.f;
            if (big) {
                float mh = kv0 ? acc10[r] : NEG;
                mh = fmaxf(mh, kv1 ? acc11[r] : NEG);
#pragma unroll
                for (int st = 1; st <= 8; st <<= 1) mh = fmaxf(mh, __shfl_xor(mh, st));
                const float f0 = kv0 ? __expf(acc10[r] - mh) : 0.f;
                const float f1 = kv1 ? __expf(acc11[r] - mh) : 0.f;
                float sh = f0 + f1;
#pragma unroll
                for (int st = 1; st <= 8; st <<= 1) sh += __shfl_xor(sh, st);
                const float invh = 1.f / sh;
                const bool qvh = (16 + kq * 4 + r) < L;
                w10[r] = qvh ? f0 * invh : 0.f;
                w11[r] = qvh ? f1 * invh : 0.f;
            }
        }
        float pa = w00[0] + w00[1] + w00[2] + w00[3];
        float pb = 0.f;
        if (big) {
            pa += w10[0] + w10[1] + w10[2] + w10[3];
            pb = w01[0] + w01[1] + w01[2] + w01[3] +
                 w11[0] + w11[1] + w11[2] + w11[3];
        }
        pa += __shfl_xor(pa, 16);
        pa += __shfl_xor(pa, 32);
        if (big) {
            pb += __shfl_xor(pb, 16);
            pb += __shfl_xor(pb, 32);
        }
        cA = pa;
        cB = pb;
    }

    // ---- Output: out[s][d] = sum_k c_k * E[start+k][d], fp16 reads ----
    if (active) {
        f32x4 o[3] = {};
        const int KP = (L + 3) & ~3;
        const _Float16* ebase = Ef + (size_t)start * Dd + lane * 4;
        for (int k = 0; k < KP; k += 4) {
            float cv[4];
            half4v ev[4][3];
#pragma unroll
            for (int j = 0; j < 4; ++j) {
                const int kk = k + j;
                cv[j] = (kk < 16) ? __shfl(cA, kk) : __shfl(cB, kk - 16);
#pragma unroll
                for (int i = 0; i < 3; ++i)
                    ev[j][i] = *reinterpret_cast<const half4v*>(ebase + (size_t)kk * Dd + i * 256);
            }
#pragma unroll
            for (int j = 0; j < 4; ++j)
#pragma unroll
                for (int i = 0; i < 3; ++i) {
                    o[i][0] += cv[j] * (float)ev[j][i][0];
                    o[i][1] += cv[j] * (float)ev[j][i][1];
                    o[i][2] += cv[j] * (float)ev[j][i][2];
                    o[i][3] += cv[j] * (float)ev[j][i][3];
                }
        }
#pragma unroll
        for (int i = 0; i < 3; ++i)
            *reinterpret_cast<f32x4*>(&out[(size_t)s * Dd + i * 256 + lane * 4]) = o[i];
    }
}

// ---------------------------------------------------------------------------
// Round-5 bf16 global span kernel (proven) — fallback tiers only.
// ---------------------------------------------------------------------------
template <bool SPLIT, bool SORTED>
__global__ __launch_bounds__(256) void span_attn_g_kernel(const __bf16* __restrict__ Eb,
                                                          const int* __restrict__ spans,
                                                          const __bf16* __restrict__ Qh,
                                                          const __bf16* __restrict__ Ql,
                                                          const int* __restrict__ perm,
                                                          float* __restrict__ out) {
    const int wave = threadIdx.x >> 6;
    const int lane = threadIdx.x & 63;

    int s;
    bool active;
    if (SORTED) {
        const int b    = blockIdx.x;
        const int bp   = (b & 7) * 313 + (b >> 3);
        const int slot = bp * 4 + wave;
        active = slot < Nn;
        int sv = active ? perm[slot] : 0;
        if ((unsigned)sv >= (unsigned)Nn) sv = 0;
        s = sv;
    } else {
        s = blockIdx.x * 4 + wave;
        active = true;
    }

    const int start = spans[2 * s];
    const int L     = spans[2 * s + 1] - start + 1;
    const bool big  = L > 16;

    const int row = lane & 15;
    const int kq  = lane >> 4;

    const size_t rbase = (size_t)(start + row) * Dd + kq * 8;
    const __bf16* qh0 = Qh + rbase;
    const __bf16* eb0 = Eb + rbase;
    const __bf16* ql0 = SPLIT ? (Ql + rbase) : nullptr;

    f32x4 acc00 = {0.f, 0.f, 0.f, 0.f};
    f32x4 acc01 = {0.f, 0.f, 0.f, 0.f};
    f32x4 acc10 = {0.f, 0.f, 0.f, 0.f};
    f32x4 acc11 = {0.f, 0.f, 0.f, 0.f};

    if (!big) {
        for (int kc = 0; kc < Dd; kc += 128) {
            bf16x8 A[4], B[4], AL[4];
#pragma unroll
            for (int j = 0; j < 4; ++j) {
                const int o = kc + j * 32;
                A[j] = *reinterpret_cast<const bf16x8*>(qh0 + o);
                B[j] = *reinterpret_cast<const bf16x8*>(eb0 + o);
                if (SPLIT) AL[j] = *reinterpret_cast<const bf16x8*>(ql0 + o);
            }
#pragma unroll
            for (int j = 0; j < 4; ++j) {
                acc00 = MFMA16(A[j], B[j], acc00);
                if (SPLIT) acc00 = MFMA16(AL[j], B[j], acc00);
            }
        }
    } else {
        for (int kc = 0; kc < Dd; kc += 64) {
            bf16x8 A0[2], A1[2], B0[2], B1[2], AL0[2], AL1[2];
#pragma unroll
            for (int j = 0; j < 2; ++j) {
                const int o = kc + j * 32;
                A0[j] = *reinterpret_cast<const bf16x8*>(qh0 + o);
                A1[j] = *reinterpret_cast<const bf16x8*>(qh0 + 16 * Dd + o);
                B0[j] = *reinterpret_cast<const bf16x8*>(eb0 + o);
                B1[j] = *reinterpret_cast<const bf16x8*>(eb0 + 16 * Dd + o);
                if (SPLIT) {
                    AL0[j] = *reinterpret_cast<const bf16x8*>(ql0 + o);
                    AL1[j] = *reinterpret_cast<const bf16x8*>(ql0 + 16 * Dd + o);
                }
            }
#pragma unroll
            for (int j = 0; j < 2; ++j) {
                acc00 = MFMA16(A0[j], B0[j], acc00);
                acc01 = MFMA16(A0[j], B1[j], acc01);
                acc10 = MFMA16(A1[j], B0[j], acc10);
                acc11 = MFMA16(A1[j], B1[j], acc11);
                if (SPLIT) {
                    acc00 = MFMA16(AL0[j], B0[j], acc00);
                    acc01 = MFMA16(AL0[j], B1[j], acc01);
                    acc10 = MFMA16(AL1[j], B0[j], acc10);
                    acc11 = MFMA16(AL1[j], B1[j], acc11);
                }
            }
        }
    }

    const float NEG = -1e30f;
    const bool kv0 = row < L;
    const bool kv1 = (16 + row) < L;
    float cA, cB;
    {
        float w00[4], w01[4], w10[4], w11[4];
#pragma unroll
        for (int r = 0; r < 4; ++r) {
            float m = kv0 ? acc00[r] : NEG;
            if (big) m = fmaxf(m, kv1 ? acc01[r] : NEG);
#pragma unroll
            for (int st = 1; st <= 8; st <<= 1) m = fmaxf(m, __shfl_xor(m, st));
            const float e0 = kv0 ? __expf(acc00[r] - m) : 0.f;
            const float e1 = (big && kv1) ? __expf(acc01[r] - m) : 0.f;
            float sum = e0 + e1;
#pragma unroll
            for (int st = 1; st <= 8; st <<= 1) sum += __shfl_xor(sum, st);
            const float inv = 1.f / sum;
            const bool qv = (kq * 4 + r) < L;
            w00[r] = qv ? e0 * inv : 0.f;
            w01[r] = qv ? e1 * inv : 0.f;
            if (big) {
                float mh = kv0 ? acc10[r] : NEG;
                mh = fmaxf(mh, kv1 ? acc11[r] : NEG);
#pragma unroll
                for (int st = 1; st <= 8; st <<= 1) mh = fmaxf(mh, __shfl_xor(mh, st));
                const float f0 = kv0 ? __expf(acc10[r] - mh) : 0.f;
                const float f1 = kv1 ? __expf(acc11[r] - mh) : 0.f;
                float sh = f0 + f1;
#pragma unroll
                for (int st = 1; st <= 8; st <<= 1) sh += __shfl_xor(sh, st);
                const float invh = 1.f / sh;
                const bool qvh = (16 + kq * 4 + r) < L;
                w10[r] = qvh ? f0 * invh : 0.f;
                w11[r] = qvh ? f1 * invh : 0.f;
            }
        }
        float pa = w00[0] + w00[1] + w00[2] + w00[3];
        float pb = 0.f;
        if (big) {
            pa += w10[0] + w10[1] + w10[2] + w10[3];
            pb = w01[0] + w01[1] + w01[2] + w01[3] +
                 w11[0] + w11[1] + w11[2] + w11[3];
        }
        pa += __shfl_xor(pa, 16);
        pa += __shfl_xor(pa, 32);
        if (big) {
            pb += __shfl_xor(pb, 16);
            pb += __shfl_xor(pb, 32);
        }
        cA = pa;
        cB = pb;
    }

    if (active) {
        f32x4 o[3] = {};
        const int KP = (L + 3) & ~3;
        const __bf16* ebase = Eb + (size_t)start * Dd + lane * 4;
        for (int k = 0; k < KP; k += 4) {
            float cv[4];
            bf16x4 ev[4][3];
#pragma unroll
            for (int j = 0; j < 4; ++j) {
                const int kk = k + j;
                cv[j] = (kk < 16) ? __shfl(cA, kk) : __shfl(cB, kk - 16);
#pragma unroll
                for (int i = 0; i < 3; ++i)
                    ev[j][i] = *reinterpret_cast<const bf16x4*>(ebase + (size_t)kk * Dd + i * 256);
            }
#pragma unroll
            for (int j = 0; j < 4; ++j)
#pragma unroll
                for (int i = 0; i < 3; ++i) {
                    o[i][0] += cv[j] * (float)ev[j][i][0];
                    o[i][1] += cv[j] * (float)ev[j][i][1];
                    o[i][2] += cv[j] * (float)ev[j][i][2];
                    o[i][3] += cv[j] * (float)ev[j][i][3];
                }
        }
#pragma unroll
        for (int i = 0; i < 3; ++i)
            *reinterpret_cast<f32x4*>(&out[(size_t)s * Dd + i * 256 + lane * 4]) = o[i];
    }
}

// ---------------------------------------------------------------------------
extern "C" void kernel_launch(void* const* d_in, const int* in_sizes, int n_in,
                              void* d_out, int out_size, void* d_ws, size_t ws_size,
                              hipStream_t stream) {
    const float* emb   = (const float*)d_in[0];
    const int*   spans = (const int*)d_in[1];
    const float* Wq    = (const float*)d_in[2];
    const float* bq    = (const float*)d_in[3];
    float*       out   = (float*)d_out;

    const size_t TD = (size_t)Tt * Dd;
    const size_t DD = (size_t)Dd * Dd;
    const int nInts = 8192 + 10016;
    const size_t intBytes = (size_t)nInts * sizeof(int);
    auto align16 = [](size_t x) { return (x + 15) & ~(size_t)15; };

    const size_t mainBf = align16((4 * TD + 2 * DD) * 2);
    const size_t needMain = mainBf + intBytes;
    const size_t needB = align16(3 * TD * 2) + intBytes;
    const size_t needC = 3 * TD * 2;

    if (ws_size >= needMain) {
        char* base = (char*)d_ws;
        _Float16* Qf = (_Float16*)base;
        _Float16* Ef = (_Float16*)(base + TD * 2);
        __bf16* Eh = (__bf16*)(base + 2 * TD * 2);
        __bf16* El = (__bf16*)(base + 3 * TD * 2);
        __bf16* Wh = (__bf16*)(base + 4 * TD * 2);
        __bf16* Wl = (__bf16*)(base + 4 * TD * 2 + DD * 2);
        int* hist = (int*)(base + mainBf);
        int* perm = hist + 8192;

        const int convBlocks = (int)((TD / 4 + DD / 4) / 256);  // 6720 exact
        conv_fused_kernel<<<convBlocks, 256, 0, stream>>>(emb, Wq, Eh, El, Ef, Wh, Wl);
        zero_kernel<<<32, 256, 0, stream>>>(hist, 8192);
        hist_kernel<<<40, 256, 0, stream>>>(spans, hist);
        scan_kernel<<<1, 256, 0, stream>>>(hist);
        scatter_kernel<<<40, 256, 0, stream>>>(spans, hist, perm);
        qproj_mfma3_kernel<<<384, 256, 0, stream>>>(Eh, El, Wh, Wl, bq, Qf);
        span_attn_win2_kernel<<<2504, 256, 0, stream>>>(Ef, spans, Qf, perm, out);
    } else if (ws_size >= needB) {
        __bf16* w = (__bf16*)d_ws;
        __bf16* Qh = w;
        __bf16* Ql = w + TD;
        __bf16* Eh = w + 2 * TD;
        int* hist = (int*)((char*)d_ws + align16(3 * TD * 2));
        int* perm = hist + 8192;

        conv_kernel<false><<<(int)(TD / 4 / 256), 256, 0, stream>>>(emb, Eh, nullptr, (int)(TD / 4));
        zero_kernel<<<32, 256, 0, stream>>>(hist, 8192);
        hist_kernel<<<40, 256, 0, stream>>>(spans, hist);
        scan_kernel<<<1, 256, 0, stream>>>(hist);
        scatter_kernel<<<40, 256, 0, stream>>>(spans, hist, perm);
        qproj_kernel<true><<<dim3(Tt / 64, Dd / 64), 256, 0, stream>>>(emb, Wq, bq, Qh, Ql);
        span_attn_g_kernel<true, true><<<2504, 256, 0, stream>>>(Eh, spans, Qh, Ql, perm, out);
    } else if (ws_size >= needC) {
        __bf16* w = (__bf16*)d_ws;
        __bf16* Qh = w;
        __bf16* Ql = w + TD;
        __bf16* Eh = w + 2 * TD;
        conv_kernel<false><<<(int)(TD / 4 / 256), 256, 0, stream>>>(emb, Eh, nullptr, (int)(TD / 4));
        qproj_kernel<true><<<dim3(Tt / 64, Dd / 64), 256, 0, stream>>>(emb, Wq, bq, Qh, Ql);
        span_attn_g_kernel<true, false><<<2500, 256, 0, stream>>>(Eh, spans, Qh, Ql, nullptr, out);
    } else {
        __bf16* w = (__bf16*)d_ws;
        __bf16* Qh = w;
        __bf16* Eh = w + TD;
        conv_kernel<false><<<(int)(TD / 4 / 256), 256, 0, stream>>>(emb, Eh, nullptr, (int)(TD / 4));
        qproj_kernel<false><<<dim3(Tt / 64, Dd / 64), 256, 0, stream>>>(emb, Wq, bq, Qh, nullptr);
        span_attn_g_kernel<false, false><<<2500, 256, 0, stream>>>(Eh, spans, Qh, nullptr, nullptr, out);
    }
}

// Round 8
// 155.632 us; speedup vs baseline: 1.1754x; 1.1754x over previous
//
#include <hip/hip_runtime.h>
#include <hip/hip_bf16.h>
#include <cstddef>
#include <cstdint>

constexpr int Tt = 8192;
constexpr int Dd = 768;
constexpr int Nn = 10000;
constexpr int Ww = 32;

typedef __bf16 bf16x8 __attribute__((ext_vector_type(8)));
typedef __bf16 bf16x4 __attribute__((ext_vector_type(4)));
typedef _Float16 half8v __attribute__((ext_vector_type(8)));
typedef _Float16 half4v __attribute__((ext_vector_type(4)));
typedef float f32x4 __attribute__((ext_vector_type(4)));

#define MFMA16(a, b, c) __builtin_amdgcn_mfma_f32_16x16x32_bf16((a), (b), (c), 0, 0, 0)
#define MFMAH(a, b, c) __builtin_amdgcn_mfma_f32_16x16x32_f16((a), (b), (c), 0, 0, 0)

// ---------------------------------------------------------------------------
// Converter: emb -> Ef (fp16), Wq -> Wf (fp16).
// ---------------------------------------------------------------------------
__global__ __launch_bounds__(256) void conv_f16_kernel(const float* __restrict__ emb,
                                                       const float* __restrict__ Wq,
                                                       _Float16* __restrict__ Ef,
                                                       _Float16* __restrict__ Wf) {
    const int nE = (Tt * Dd) / 4;
    const int nW = (Dd * Dd) / 4;
    const int i = blockIdx.x * 256 + threadIdx.x;
    if (i < nE) {
        const float4 v = reinterpret_cast<const float4*>(emb)[i];
        half4v o;
        o[0] = (_Float16)v.x; o[1] = (_Float16)v.y;
        o[2] = (_Float16)v.z; o[3] = (_Float16)v.w;
        reinterpret_cast<half4v*>(Ef)[i] = o;
    } else {
        const int j = i - nE;
        if (j < nW) {
            const float4 v = reinterpret_cast<const float4*>(Wq)[j];
            half4v o;
            o[0] = (_Float16)v.x; o[1] = (_Float16)v.y;
            o[2] = (_Float16)v.z; o[3] = (_Float16)v.w;
            reinterpret_cast<half4v*>(Wf)[j] = o;
        }
    }
}

// Simple bf16 converter for fallback tiers.
template <bool LO>
__global__ __launch_bounds__(256) void conv_kernel(const float* __restrict__ src,
                                                   __bf16* __restrict__ h,
                                                   __bf16* __restrict__ l, int n4) {
    const int i = blockIdx.x * 256 + threadIdx.x;
    if (i >= n4) return;
    const float4 v = reinterpret_cast<const float4*>(src)[i];
    bf16x4 oh, ol;
    oh[0] = (__bf16)v.x; oh[1] = (__bf16)v.y; oh[2] = (__bf16)v.z; oh[3] = (__bf16)v.w;
    reinterpret_cast<bf16x4*>(h)[i] = oh;
    if (LO) {
        ol[0] = (__bf16)(v.x - (float)oh[0]);
        ol[1] = (__bf16)(v.y - (float)oh[1]);
        ol[2] = (__bf16)(v.z - (float)oh[2]);
        ol[3] = (__bf16)(v.w - (float)oh[3]);
        reinterpret_cast<bf16x4*>(l)[i] = ol;
    }
}

// ---------------------------------------------------------------------------
// Counting sort of span indices by start. Rebuilt fully every call.
// ---------------------------------------------------------------------------
__global__ __launch_bounds__(256) void zero_kernel(int* __restrict__ p, int n) {
    const int i = blockIdx.x * 256 + threadIdx.x;
    if (i < n) p[i] = 0;
}

__global__ __launch_bounds__(256) void hist_kernel(const int* __restrict__ spans,
                                                   int* __restrict__ hist) {
    const int i = blockIdx.x * 256 + threadIdx.x;
    if (i < Nn) atomicAdd(&hist[spans[2 * i]], 1);
}

__global__ __launch_bounds__(256) void scan_kernel(int* __restrict__ hist) {
    __shared__ int part[256];
    const int t = threadIdx.x;
    int vals[32];
    int sum = 0;
#pragma unroll
    for (int i = 0; i < 32; ++i) { vals[i] = hist[t * 32 + i]; sum += vals[i]; }
    part[t] = sum;
    __syncthreads();
    for (int off = 1; off < 256; off <<= 1) {
        const int v = (t >= off) ? part[t - off] : 0;
        __syncthreads();
        part[t] += v;
        __syncthreads();
    }
    int run = (t == 0) ? 0 : part[t - 1];
#pragma unroll
    for (int i = 0; i < 32; ++i) { const int v = vals[i]; hist[t * 32 + i] = run; run += v; }
}

__global__ __launch_bounds__(256) void scatter_kernel(const int* __restrict__ spans,
                                                      int* __restrict__ offs,
                                                      int* __restrict__ perm) {
    const int i = blockIdx.x * 256 + threadIdx.x;
    if (i < Nn) {
        const int p = atomicAdd(&offs[spans[2 * i]], 1);
        perm[p] = i;
    }
}

// ---------------------------------------------------------------------------
// fp32 vector qproj (fallback tiers). Q = emb @ Wq^T + bq, bf16 hi/lo out.
// ---------------------------------------------------------------------------
template <bool SPLIT>
__global__ __launch_bounds__(256) void qproj_kernel(const float* __restrict__ emb,
                                                    const float* __restrict__ Wq,
                                                    const float* __restrict__ bq,
                                                    __bf16* __restrict__ Qh,
                                                    __bf16* __restrict__ Ql) {
    __shared__ float As[64][32];
    __shared__ float Bs[64][32];
    const int tid = threadIdx.x;
    const int tx = tid & 15;
    const int ty = tid >> 4;
    const int m0 = blockIdx.x * 64;
    const int n0 = blockIdx.y * 64;

    float acc[4][4] = {};

    for (int kc = 0; kc < Dd; kc += 32) {
#pragma unroll
        for (int i = 0; i < 2; ++i) {
            const int f   = tid + i * 256;
            const int row = f >> 3;
            const int c4  = f & 7;
            const int ph  = (c4 + (row >> 2)) & 7;
            *reinterpret_cast<float4*>(&As[row][ph * 4]) =
                *reinterpret_cast<const float4*>(&emb[(size_t)(m0 + row) * Dd + kc + c4 * 4]);
            *reinterpret_cast<float4*>(&Bs[row][ph * 4]) =
                *reinterpret_cast<const float4*>(&Wq[(size_t)(n0 + row) * Dd + kc + c4 * 4]);
        }
        __syncthreads();
#pragma unroll
        for (int d4 = 0; d4 < 8; ++d4) {
            float4 av[4], bv[4];
#pragma unroll
            for (int r = 0; r < 4; ++r)
                av[r] = *reinterpret_cast<const float4*>(&As[ty * 4 + r][((d4 + ty) & 7) * 4]);
#pragma unroll
            for (int c = 0; c < 4; ++c)
                bv[c] = *reinterpret_cast<const float4*>(&Bs[tx * 4 + c][((d4 + tx) & 7) * 4]);
#pragma unroll
            for (int r = 0; r < 4; ++r)
#pragma unroll
                for (int c = 0; c < 4; ++c) {
                    acc[r][c] += av[r].x * bv[c].x;
                    acc[r][c] += av[r].y * bv[c].y;
                    acc[r][c] += av[r].z * bv[c].z;
                    acc[r][c] += av[r].w * bv[c].w;
                }
        }
        __syncthreads();
    }
#pragma unroll
    for (int r = 0; r < 4; ++r) {
        bf16x4 oh, ol;
#pragma unroll
        for (int c = 0; c < 4; ++c) {
            const float v = acc[r][c] + bq[n0 + tx * 4 + c];
            const __bf16 h = (__bf16)v;
            oh[c] = h;
            if (SPLIT) ol[c] = (__bf16)(v - (float)h);
        }
        const size_t off = (size_t)(m0 + ty * 4 + r) * Dd + n0 + tx * 4;
        *reinterpret_cast<bf16x4*>(&Qh[off]) = oh;
        if (SPLIT) *reinterpret_cast<bf16x4*>(&Ql[off]) = ol;
    }
}

// ---------------------------------------------------------------------------
// qproj fp16 single-term: Qf = Ef @ Wf^T + bq (fp32 acc, fp16 out).
// 128x96 tile, grid 512 (2 blocks/CU exact), 4 waves x 64x48, BK=64,
// sync staging, source-permuted octets (o ^ (row&7)) -> 2-way (free) reads.
// Precision: Qf is fp16 anyway (5e-4); fp16-input error adds ~4e-4 -> score
// delta ~0.01, invisible vs 0.25 absmax.
// ---------------------------------------------------------------------------
__global__ __launch_bounds__(256) void qproj_f16_kernel(const _Float16* __restrict__ Ef,
                                                        const _Float16* __restrict__ Wf,
                                                        const float* __restrict__ bq,
                                                        _Float16* __restrict__ Qf) {
    __shared__ __align__(16) _Float16 As[128 * 64];  // 16 KB
    __shared__ __align__(16) _Float16 Bs[96 * 64];   // 12 KB

    const int tid  = threadIdx.x;
    const int wave = tid >> 6;
    const int lane = tid & 63;

    const int b   = blockIdx.x;        // 0..511
    const int xcd = b & 7;
    const int li  = b >> 3;            // 0..63
    const int mt  = xcd * 8 + (li >> 3);  // 0..63 ; 8 n-tiles per m share XCD
    const int nt  = li & 7;            // 0..7
    const int m0 = mt * 128;
    const int n0 = nt * 96;
    const int wm = (wave & 1) * 64;
    const int wn = (wave >> 1) * 48;
    const int fr = lane & 15;
    const int kg = lane >> 4;

    // Staging geometry. A: 1024 segs (4/thread), B: 768 segs (3/thread).
    // Seg s -> row r = s>>3, LDS octet o = s&7 holding GLOBAL octet o^(r&7).
    int ar[4], ao[4];
#pragma unroll
    for (int i = 0; i < 4; ++i) {
        const int s = tid + i * 256;
        ar[i] = s >> 3;
        ao[i] = ((s & 7) ^ (ar[i] & 7)) * 8;
    }
    int br[3], bo[3];
#pragma unroll
    for (int i = 0; i < 3; ++i) {
        const int s = tid + i * 256;
        br[i] = s >> 3;
        bo[i] = ((s & 7) ^ (br[i] & 7)) * 8;
    }

    f32x4 acc[4][3] = {};

    for (int kc = 0; kc < Dd; kc += 64) {
        half8v ra[4], rb[3];
#pragma unroll
        for (int i = 0; i < 4; ++i)
            ra[i] = *reinterpret_cast<const half8v*>(&Ef[(size_t)(m0 + ar[i]) * Dd + kc + ao[i]]);
#pragma unroll
        for (int i = 0; i < 3; ++i)
            rb[i] = *reinterpret_cast<const half8v*>(&Wf[(size_t)(n0 + br[i]) * Dd + kc + bo[i]]);
        __syncthreads();  // previous iteration's LDS reads complete
#pragma unroll
        for (int i = 0; i < 4; ++i)
            *reinterpret_cast<half8v*>(&As[(tid + i * 256) * 8]) = ra[i];
#pragma unroll
        for (int i = 0; i < 3; ++i)
            *reinterpret_cast<half8v*>(&Bs[(tid + i * 256) * 8]) = rb[i];
        __syncthreads();  // writes visible

#pragma unroll
        for (int step = 0; step < 2; ++step) {
            const int g = kg + 4 * step;  // global octet within 64-col chunk
            half8v a[4], bb[3];
#pragma unroll
            for (int r = 0; r < 4; ++r) {
                const int R = wm + r * 16 + fr;
                a[r] = *reinterpret_cast<const half8v*>(&As[R * 64 + (g ^ (R & 7)) * 8]);
            }
#pragma unroll
            for (int c = 0; c < 3; ++c) {
                const int R = wn + c * 16 + fr;
                bb[c] = *reinterpret_cast<const half8v*>(&Bs[R * 64 + (g ^ (R & 7)) * 8]);
            }
#pragma unroll
            for (int r = 0; r < 4; ++r)
#pragma unroll
                for (int c = 0; c < 3; ++c)
                    acc[r][c] = MFMAH(a[r], bb[c], acc[r][c]);
        }
    }

    // Epilogue: C/D layout col=lane&15, row=(lane>>4)*4+reg.
#pragma unroll
    for (int c = 0; c < 3; ++c) {
        const int ocol = n0 + wn + c * 16 + fr;
        const float bqv = bq[ocol];
#pragma unroll
        for (int r = 0; r < 4; ++r)
#pragma unroll
            for (int j = 0; j < 4; ++j) {
                const int orow = m0 + wm + r * 16 + kg * 4 + j;
                Qf[(size_t)orow * Dd + ocol] = (_Float16)(acc[r][c][j] + bqv);
            }
    }
}

// ---------------------------------------------------------------------------
// Span attention (round-6 verbatim, 54 us proven): fp16, window-shared LDS,
// single-buffered sync staging, ST=136; softmax + col sums in registers.
// ---------------------------------------------------------------------------
__global__ __launch_bounds__(256) void span_attn_win_kernel(const _Float16* __restrict__ Ef,
                                                            const int* __restrict__ spans,
                                                            const _Float16* __restrict__ Qf,
                                                            const int* __restrict__ perm,
                                                            float* __restrict__ out) {
    constexpr int WR = 48, CH = 128, ST = 136, NCH = Dd / CH;
    __shared__ __align__(16) _Float16 Qs[WR * ST];
    __shared__ __align__(16) _Float16 Es[WR * ST];

    const int tid  = threadIdx.x;
    const int wave = tid >> 6;
    const int lane = tid & 63;

    const int b     = blockIdx.x;
    const int bp    = (b & 7) * 313 + (b >> 3);
    const int slot0 = bp * 4;
    const int slot  = slot0 + wave;
    const bool active = slot < Nn;

    int s0 = perm[slot0 < Nn ? slot0 : (Nn - 1)];
    if ((unsigned)s0 >= (unsigned)Nn) s0 = 0;
    int s = active ? perm[slot] : s0;
    if ((unsigned)s >= (unsigned)Nn) s = 0;

    const int w0    = spans[2 * s0];
    const int start = spans[2 * s];
    const int L     = spans[2 * s + 1] - start + 1;  // 1..32
    const bool big  = L > 16;
    const int sl    = start - w0;
    const bool inwin = active && sl >= 0 && sl <= (WR - 32);

    const int row = lane & 15;  // A-frag m; C-col k
    const int kq  = lane >> 4;

    const size_t gq = (size_t)(start + row) * Dd + kq * 8;  // fallback base

    f32x4 acc00 = {0.f, 0.f, 0.f, 0.f};
    f32x4 acc01 = {0.f, 0.f, 0.f, 0.f};
    f32x4 acc10 = {0.f, 0.f, 0.f, 0.f};
    f32x4 acc11 = {0.f, 0.f, 0.f, 0.f};

    for (int c = 0; c < NCH; ++c) {
        const int c0 = c * CH;
        __syncthreads();  // previous chunk's LDS reads complete
#pragma unroll
        for (int i = 0; i < 3; ++i) {
            const int seg = tid + i * 256;  // 768 segs: 48 rows x 16 col-segs
            const int r  = seg >> 4;
            const int cs = seg & 15;
            const int gr = w0 + r < Tt ? w0 + r : Tt - 1;  // clamp (pad rows unused)
            const size_t ga = (size_t)gr * Dd + c0 + cs * 8;
            *reinterpret_cast<half8v*>(&Qs[r * ST + cs * 8]) =
                *reinterpret_cast<const half8v*>(&Qf[ga]);
            *reinterpret_cast<half8v*>(&Es[r * ST + cs * 8]) =
                *reinterpret_cast<const half8v*>(&Ef[ga]);
        }
        __syncthreads();

        if (inwin) {
            const int ab = (sl + row) * ST + kq * 8;
#pragma unroll
            for (int j = 0; j < 4; ++j) {
                const int o = j * 32;
                const half8v a0 = *reinterpret_cast<const half8v*>(&Qs[ab + o]);
                const half8v b0 = *reinterpret_cast<const half8v*>(&Es[ab + o]);
                acc00 = MFMAH(a0, b0, acc00);
                if (big) {
                    const half8v a1 = *reinterpret_cast<const half8v*>(&Qs[ab + 16 * ST + o]);
                    const half8v b1 = *reinterpret_cast<const half8v*>(&Es[ab + 16 * ST + o]);
                    acc01 = MFMAH(a0, b1, acc01);
                    acc10 = MFMAH(a1, b0, acc10);
                    acc11 = MFMAH(a1, b1, acc11);
                }
            }
        } else if (active) {
            // rare: span exceeds window — direct global fragment loads
#pragma unroll
            for (int j = 0; j < 4; ++j) {
                const int o = c0 + j * 32;
                const half8v a0 = *reinterpret_cast<const half8v*>(&Qf[gq + o]);
                const half8v b0 = *reinterpret_cast<const half8v*>(&Ef[gq + o]);
                acc00 = MFMAH(a0, b0, acc00);
                if (big) {
                    const half8v a1 = *reinterpret_cast<const half8v*>(&Qf[gq + 16 * Dd + o]);
                    const half8v b1 = *reinterpret_cast<const half8v*>(&Ef[gq + 16 * Dd + o]);
                    acc01 = MFMAH(a0, b1, acc01);
                    acc10 = MFMAH(a1, b0, acc10);
                    acc11 = MFMAH(a1, b1, acc11);
                }
            }
        }
    }

    // ---- In-register softmax + column sums ----
    const float NEG = -1e30f;
    const bool kv0 = row < L;
    const bool kv1 = (16 + row) < L;
    float cA, cB;
    {
        float w00[4], w01[4], w10[4], w11[4];
#pragma unroll
        for (int r = 0; r < 4; ++r) {
            float m = kv0 ? acc00[r] : NEG;
            if (big) m = fmaxf(m, kv1 ? acc01[r] : NEG);
#pragma unroll
            for (int st = 1; st <= 8; st <<= 1) m = fmaxf(m, __shfl_xor(m, st));
            const float e0 = kv0 ? __expf(acc00[r] - m) : 0.f;
            const float e1 = (big && kv1) ? __expf(acc01[r] - m) : 0.f;
            float sum = e0 + e1;
#pragma unroll
            for (int st = 1; st <= 8; st <<= 1) sum += __shfl_xor(sum, st);
            const float inv = 1.f / sum;
            const bool qv = (kq * 4 + r) < L;
            w00[r] = qv ? e0 * inv : 0.f;
            w01[r] = qv ? e1 * inv : 0.f;
            if (big) {
                float mh = kv0 ? acc10[r] : NEG;
                mh = fmaxf(mh, kv1 ? acc11[r] : NEG);
#pragma unroll
                for (int st = 1; st <= 8; st <<= 1) mh = fmaxf(mh, __shfl_xor(mh, st));
                const float f0 = kv0 ? __expf(acc10[r] - mh) : 0.f;
                const float f1 = kv1 ? __expf(acc11[r] - mh) : 0.f;
                float sh = f0 + f1;
#pragma unroll
                for (int st = 1; st <= 8; st <<= 1) sh += __shfl_xor(sh, st);
                const float invh = 1.f / sh;
                const bool qvh = (16 + kq * 4 + r) < L;
                w10[r] = qvh ? f0 * invh : 0.f;
                w11[r] = qvh ? f1 * invh : 0.f;
            }
        }
        float pa = w00[0] + w00[1] + w00[2] + w00[3];
        float pb = 0.f;
        if (big) {
            pa += w10[0] + w10[1] + w10[2] + w10[3];
            pb = w01[0] + w01[1] + w01[2] + w01[3] +
                 w11[0] + w11[1] + w11[2] + w11[3];
        }
        pa += __shfl_xor(pa, 16);
        pa += __shfl_xor(pa, 32);
        if (big) {
            pb += __shfl_xor(pb, 16);
            pb += __shfl_xor(pb, 32);
        }
        cA = pa;
        cB = pb;
    }

    // ---- Output: out[s][d] = sum_k c_k * E[start+k][d], fp16 reads ----
    if (active) {
        f32x4 o[3] = {};
        const int KP = (L + 3) & ~3;
        const _Float16* ebase = Ef + (size_t)start * Dd + lane * 4;
        for (int k = 0; k < KP; k += 4) {
            float cv[4];
            half4v ev[4][3];
#pragma unroll
            for (int j = 0; j < 4; ++j) {
                const int kk = k + j;
                cv[j] = (kk < 16) ? __shfl(cA, kk) : __shfl(cB, kk - 16);
#pragma unroll
                for (int i = 0; i < 3; ++i)
                    ev[j][i] = *reinterpret_cast<const half4v*>(ebase + (size_t)kk * Dd + i * 256);
            }
#pragma unroll
            for (int j = 0; j < 4; ++j)
#pragma unroll
                for (int i = 0; i < 3; ++i) {
                    o[i][0] += cv[j] * (float)ev[j][i][0];
                    o[i][1] += cv[j] * (float)ev[j][i][1];
                    o[i][2] += cv[j] * (float)ev[j][i][2];
                    o[i][3] += cv[j] * (float)ev[j][i][3];
                }
        }
#pragma unroll
        for (int i = 0; i < 3; ++i)
            *reinterpret_cast<f32x4*>(&out[(size_t)s * Dd + i * 256 + lane * 4]) = o[i];
    }
}

// ---------------------------------------------------------------------------
// Round-5 bf16 global span kernel (proven) — fallback tiers only.
// ---------------------------------------------------------------------------
template <bool SPLIT, bool SORTED>
__global__ __launch_bounds__(256) void span_attn_g_kernel(const __bf16* __restrict__ Eb,
                                                          const int* __restrict__ spans,
                                                          const __bf16* __restrict__ Qh,
                                                          const __bf16* __restrict__ Ql,
                                                          const int* __restrict__ perm,
                                                          float* __restrict__ out) {
    const int wave = threadIdx.x >> 6;
    const int lane = threadIdx.x & 63;

    int s;
    bool active;
    if (SORTED) {
        const int b    = blockIdx.x;
        const int bp   = (b & 7) * 313 + (b >> 3);
        const int slot = bp * 4 + wave;
        active = slot < Nn;
        int sv = active ? perm[slot] : 0;
        if ((unsigned)sv >= (unsigned)Nn) sv = 0;
        s = sv;
    } else {
        s = blockIdx.x * 4 + wave;
        active = true;
    }

    const int start = spans[2 * s];
    const int L     = spans[2 * s + 1] - start + 1;
    const bool big  = L > 16;

    const int row = lane & 15;
    const int kq  = lane >> 4;

    const size_t rbase = (size_t)(start + row) * Dd + kq * 8;
    const __bf16* qh0 = Qh + rbase;
    const __bf16* eb0 = Eb + rbase;
    const __bf16* ql0 = SPLIT ? (Ql + rbase) : nullptr;

    f32x4 acc00 = {0.f, 0.f, 0.f, 0.f};
    f32x4 acc01 = {0.f, 0.f, 0.f, 0.f};
    f32x4 acc10 = {0.f, 0.f, 0.f, 0.f};
    f32x4 acc11 = {0.f, 0.f, 0.f, 0.f};

    if (!big) {
        for (int kc = 0; kc < Dd; kc += 128) {
            bf16x8 A[4], B[4], AL[4];
#pragma unroll
            for (int j = 0; j < 4; ++j) {
                const int o = kc + j * 32;
                A[j] = *reinterpret_cast<const bf16x8*>(qh0 + o);
                B[j] = *reinterpret_cast<const bf16x8*>(eb0 + o);
                if (SPLIT) AL[j] = *reinterpret_cast<const bf16x8*>(ql0 + o);
            }
#pragma unroll
            for (int j = 0; j < 4; ++j) {
                acc00 = MFMA16(A[j], B[j], acc00);
                if (SPLIT) acc00 = MFMA16(AL[j], B[j], acc00);
            }
        }
    } else {
        for (int kc = 0; kc < Dd; kc += 64) {
            bf16x8 A0[2], A1[2], B0[2], B1[2], AL0[2], AL1[2];
#pragma unroll
            for (int j = 0; j < 2; ++j) {
                const int o = kc + j * 32;
                A0[j] = *reinterpret_cast<const bf16x8*>(qh0 + o);
                A1[j] = *reinterpret_cast<const bf16x8*>(qh0 + 16 * Dd + o);
                B0[j] = *reinterpret_cast<const bf16x8*>(eb0 + o);
                B1[j] = *reinterpret_cast<const bf16x8*>(eb0 + 16 * Dd + o);
                if (SPLIT) {
                    AL0[j] = *reinterpret_cast<const bf16x8*>(ql0 + o);
                    AL1[j] = *reinterpret_cast<const bf16x8*>(ql0 + 16 * Dd + o);
                }
            }
#pragma unroll
            for (int j = 0; j < 2; ++j) {
                acc00 = MFMA16(A0[j], B0[j], acc00);
                acc01 = MFMA16(A0[j], B1[j], acc01);
                acc10 = MFMA16(A1[j], B0[j], acc10);
                acc11 = MFMA16(A1[j], B1[j], acc11);
                if (SPLIT) {
                    acc00 = MFMA16(AL0[j], B0[j], acc00);
                    acc01 = MFMA16(AL0[j], B1[j], acc01);
                    acc10 = MFMA16(AL1[j], B0[j], acc10);
                    acc11 = MFMA16(AL1[j], B1[j], acc11);
                }
            }
        }
    }

    const float NEG = -1e30f;
    const bool kv0 = row < L;
    const bool kv1 = (16 + row) < L;
    float cA, cB;
    {
        float w00[4], w01[4], w10[4], w11[4];
#pragma unroll
        for (int r = 0; r < 4; ++r) {
            float m = kv0 ? acc00[r] : NEG;
            if (big) m = fmaxf(m, kv1 ? acc01[r] : NEG);
#pragma unroll
            for (int st = 1; st <= 8; st <<= 1) m = fmaxf(m, __shfl_xor(m, st));
            const float e0 = kv0 ? __expf(acc00[r] - m) : 0.f;
            const float e1 = (big && kv1) ? __expf(acc01[r] - m) : 0.f;
            float sum = e0 + e1;
#pragma unroll
            for (int st = 1; st <= 8; st <<= 1) sum += __shfl_xor(sum, st);
            const float inv = 1.f / sum;
            const bool qv = (kq * 4 + r) < L;
            w00[r] = qv ? e0 * inv : 0.f;
            w01[r] = qv ? e1 * inv : 0.f;
            if (big) {
                float mh = kv0 ? acc10[r] : NEG;
                mh = fmaxf(mh, kv1 ? acc11[r] : NEG);
#pragma unroll
                for (int st = 1; st <= 8; st <<= 1) mh = fmaxf(mh, __shfl_xor(mh, st));
                const float f0 = kv0 ? __expf(acc10[r] - mh) : 0.f;
                const float f1 = kv1 ? __expf(acc11[r] - mh) : 0.f;
                float sh = f0 + f1;
#pragma unroll
                for (int st = 1; st <= 8; st <<= 1) sh += __shfl_xor(sh, st);
                const float invh = 1.f / sh;
                const bool qvh = (16 + kq * 4 + r) < L;
                w10[r] = qvh ? f0 * invh : 0.f;
                w11[r] = qvh ? f1 * invh : 0.f;
            }
        }
        float pa = w00[0] + w00[1] + w00[2] + w00[3];
        float pb = 0.f;
        if (big) {
            pa += w10[0] + w10[1] + w10[2] + w10[3];
            pb = w01[0] + w01[1] + w01[2] + w01[3] +
                 w11[0] + w11[1] + w11[2] + w11[3];
        }
        pa += __shfl_xor(pa, 16);
        pa += __shfl_xor(pa, 32);
        if (big) {
            pb += __shfl_xor(pb, 16);
            pb += __shfl_xor(pb, 32);
        }
        cA = pa;
        cB = pb;
    }

    if (active) {
        f32x4 o[3] = {};
        const int KP = (L + 3) & ~3;
        const __bf16* ebase = Eb + (size_t)start * Dd + lane * 4;
        for (int k = 0; k < KP; k += 4) {
            float cv[4];
            bf16x4 ev[4][3];
#pragma unroll
            for (int j = 0; j < 4; ++j) {
                const int kk = k + j;
                cv[j] = (kk < 16) ? __shfl(cA, kk) : __shfl(cB, kk - 16);
#pragma unroll
                for (int i = 0; i < 3; ++i)
                    ev[j][i] = *reinterpret_cast<const bf16x4*>(ebase + (size_t)kk * Dd + i * 256);
            }
#pragma unroll
            for (int j = 0; j < 4; ++j)
#pragma unroll
                for (int i = 0; i < 3; ++i) {
                    o[i][0] += cv[j] * (float)ev[j][i][0];
                    o[i][1] += cv[j] * (float)ev[j][i][1];
                    o[i][2] += cv[j] * (float)ev[j][i][2];
                    o[i][3] += cv[j] * (float)ev[j][i][3];
                }
        }
#pragma unroll
        for (int i = 0; i < 3; ++i)
            *reinterpret_cast<f32x4*>(&out[(size_t)s * Dd + i * 256 + lane * 4]) = o[i];
    }
}

// ---------------------------------------------------------------------------
extern "C" void kernel_launch(void* const* d_in, const int* in_sizes, int n_in,
                              void* d_out, int out_size, void* d_ws, size_t ws_size,
                              hipStream_t stream) {
    const float* emb   = (const float*)d_in[0];
    const int*   spans = (const int*)d_in[1];
    const float* Wq    = (const float*)d_in[2];
    const float* bq    = (const float*)d_in[3];
    float*       out   = (float*)d_out;

    const size_t TD = (size_t)Tt * Dd;
    const size_t DD = (size_t)Dd * Dd;
    const size_t intBytes = (size_t)(8192 + 10016) * sizeof(int);
    auto align16 = [](size_t x) { return (x + 15) & ~(size_t)15; };

    const size_t needMain = align16((2 * TD + DD) * 2) + intBytes;  // ~26.6 MB
    const size_t needB = align16(3 * TD * 2) + intBytes;
    const size_t needC = 3 * TD * 2;

    if (ws_size >= needMain) {
        char* base = (char*)d_ws;
        _Float16* Qf = (_Float16*)base;
        _Float16* Ef = (_Float16*)(base + TD * 2);
        _Float16* Wf = (_Float16*)(base + 2 * TD * 2);
        int* hist = (int*)(base + align16((2 * TD + DD) * 2));
        int* perm = hist + 8192;

        const int convBlocks = (int)((TD / 4 + DD / 4) / 256);  // 6720 exact
        conv_f16_kernel<<<convBlocks, 256, 0, stream>>>(emb, Wq, Ef, Wf);
        zero_kernel<<<32, 256, 0, stream>>>(hist, 8192);
        hist_kernel<<<40, 256, 0, stream>>>(spans, hist);
        scan_kernel<<<1, 256, 0, stream>>>(hist);
        scatter_kernel<<<40, 256, 0, stream>>>(spans, hist, perm);
        qproj_f16_kernel<<<512, 256, 0, stream>>>(Ef, Wf, bq, Qf);
        span_attn_win_kernel<<<2504, 256, 0, stream>>>(Ef, spans, Qf, perm, out);
    } else if (ws_size >= needB) {
        __bf16* w = (__bf16*)d_ws;
        __bf16* Qh = w;
        __bf16* Ql = w + TD;
        __bf16* Eh = w + 2 * TD;
        int* hist = (int*)((char*)d_ws + align16(3 * TD * 2));
        int* perm = hist + 8192;

        conv_kernel<false><<<(int)(TD / 4 / 256), 256, 0, stream>>>(emb, Eh, nullptr, (int)(TD / 4));
        zero_kernel<<<32, 256, 0, stream>>>(hist, 8192);
        hist_kernel<<<40, 256, 0, stream>>>(spans, hist);
        scan_kernel<<<1, 256, 0, stream>>>(hist);
        scatter_kernel<<<40, 256, 0, stream>>>(spans, hist, perm);
        qproj_kernel<true><<<dim3(Tt / 64, Dd / 64), 256, 0, stream>>>(emb, Wq, bq, Qh, Ql);
        span_attn_g_kernel<true, true><<<2504, 256, 0, stream>>>(Eh, spans, Qh, Ql, perm, out);
    } else if (ws_size >= needC) {
        __bf16* w = (__bf16*)d_ws;
        __bf16* Qh = w;
        __bf16* Ql = w + TD;
        __bf16* Eh = w + 2 * TD;
        conv_kernel<false><<<(int)(TD / 4 / 256), 256, 0, stream>>>(emb, Eh, nullptr, (int)(TD / 4));
        qproj_kernel<true><<<dim3(Tt / 64, Dd / 64), 256, 0, stream>>>(emb, Wq, bq, Qh, Ql);
        span_attn_g_kernel<true, false><<<2500, 256, 0, stream>>>(Eh, spans, Qh, Ql, nullptr, out);
    } else {
        __bf16* w = (__bf16*)d_ws;
        __bf16* Qh = w;
        __bf16* Eh = w + TD;
        conv_kernel<false><<<(int)(TD / 4 / 256), 256, 0, stream>>>(emb, Eh, nullptr, (int)(TD / 4));
        qproj_kernel<false><<<dim3(Tt / 64, Dd / 64), 256, 0, stream>>>(emb, Wq, bq, Qh, nullptr);
        span_attn_g_kernel<false, false><<<2500, 256, 0, stream>>>(Eh, spans, Qh, nullptr, nullptr, out);
    }
}